// Round 8
// baseline (215.612 us; speedup 1.0000x reference)
//
#include <hip/hip_runtime.h>
#include <math.h>

#define D_MODEL 1024
#define N_STATE 64
#define BATCH   16
#define SEQ     1024
#define CS      16          // scan steps per LDS chunk
#define SEGLEN  512         // steps stored per segment
#define WARM    64          // warmup steps for segment 1 (0.7311^64 ~ 2e-9)
#define SAT_T   1.0001f     // saturation margin (covers fp32 rounding)
#define LPS     20          // lpxT row stride (pad; rows stay 16B-aligned)

__device__ __forceinline__ float sigmoidf_dev(float v) {
    return 1.0f / (1.0f + expf(-v));
}

// DPP add: v += v[partner] within an aligned 16-lane row. Pure VALU, no LDS.
// 0xB1 = quad_perm [1,0,3,2] (xor1), 0x4E = quad_perm [2,3,0,1] (xor2),
// 0x141 = row_half_mirror (acts as xor4 on quad-uniform values),
// 0x140 = row_mirror (acts as xor8 on half-row-uniform values).
template<int CTRL>
__device__ __forceinline__ float dpp_add(float v) {
    int s = __builtin_amdgcn_update_dpp(0, __float_as_int(v), CTRL, 0xF, 0xF, true);
    return v + __int_as_float(s);
}

template<int CTRL>
__device__ __forceinline__ float dpp_min(float v) {
    int s = __builtin_amdgcn_update_dpp(0, __float_as_int(v), CTRL, 0xF, 0xF, true);
    return fminf(v, __int_as_float(s));
}

#define CLAMP01(v) __builtin_amdgcn_fmed3f((v), 0.0f, 1.0f)

// ---------------------------------------------------------------------------
// k0 (merged): blocks 0..255 precompute sigmoid(A), BwT, Cs, gs.
// Blocks 256..259 compute csum[d] = sum_n sigmoid(W_C[d][n]) in EXACTLY the
// op order of k2's slow path with h==1 (per-quad (c0+c1)+(c2+c3), balanced
// XOR tree off=1,2,4,8) — sigmoidf_dev(W_C[i]) is bitwise-identical to the
// Cs value k2 uses, so the substitution in k3 stays bit-exact.
// ---------------------------------------------------------------------------
__global__ __launch_bounds__(256) void k0_precompute(
        const float* __restrict__ A, const float* __restrict__ W_B,
        const float* __restrict__ W_C, const float* __restrict__ gamma,
        float* __restrict__ A_sig, float* __restrict__ BwT,
        float* __restrict__ Cs, float* __restrict__ gs,
        float* __restrict__ csum) {
    const int bid = blockIdx.x;
    const int t   = threadIdx.x;
    if (bid < 256) {
        int i = bid * 256 + t;
        A_sig[i] = sigmoidf_dev(A[i]);
        Cs[i]    = sigmoidf_dev(W_C[i]);
        int d = i >> 6, n = i & 63;                  // i = d*64 + n
        BwT[i] = sigmoidf_dev(W_B[n * D_MODEL + d]); // W_B is [N, D]
        if (i < D_MODEL) gs[i] = sigmoidf_dev(gamma[i]);
    } else {
        int d = (bid - 256) * 256 + t;               // 0..1023
        const float4* c = (const float4*)(W_C + (size_t)d * N_STATE);
        float w[16];
#pragma unroll
        for (int q = 0; q < 16; ++q) {
            float4 v = c[q];
            w[q] = (sigmoidf_dev(v.x) + sigmoidf_dev(v.y)) +
                   (sigmoidf_dev(v.z) + sigmoidf_dev(v.w));
        }
#pragma unroll
        for (int off = 1; off < 16; off <<= 1) {
            float tmp[16];
#pragma unroll
            for (int q = 0; q < 16; ++q) tmp[q] = w[q] + w[q ^ off];
#pragma unroll
            for (int q = 0; q < 16; ++q) w[q] = tmp[q];
        }
        csum[d] = w[0];
    }
}

// ---------------------------------------------------------------------------
// k1: bt[m][n] = sum_d x[m][d] * BwT[d][n]  (M=16384, K=1024, N=64, fp32)
// Split-K within the block (round 7). Block = 512 threads (8 waves); group
// g = t>>8 accumulates k in [g*512, g*512+512) sequentially (kt asc, kk asc).
// Group 1 publishes partials via LDS scalar planes; group 0 adds, stores bt
// and btmin. Grid 256 -> 8 waves/CU, 2 waves/SIMD, 2 B/FMA.
// ---------------------------------------------------------------------------
__global__ __launch_bounds__(512) void k1_bt_gemm(
        const float* __restrict__ x, const float* __restrict__ BwT,
        float* __restrict__ bt, float* __restrict__ btmin) {
    __shared__ float xs[2][2][16][68];   // [grp][buf][k][m(64)+4 pad]
    __shared__ float bs[2][2][16][64];   // [grp][buf][k][n]
    __shared__ float accb[16][256];      // group-1 partials, scalar planes

    const int t   = threadIdx.x;
    const int g   = t >> 8;           // k-half group
    const int tid = t & 255;
    const int r   = tid >> 4;         // 0..15 -> m rows r*4 .. r*4+3
    const int c   = tid & 15;         // 0..15 -> n quad c*4
    const int m0  = blockIdx.x * 64;
    const int kb  = g * 512;          // k base for this group

    const int sm  = tid >> 2;         // staging: m row 0..63
    const int sk4 = (tid & 3) * 4;    // staging: k quad 0,4,8,12

    float acc[4][4];
#pragma unroll
    for (int i = 0; i < 4; ++i)
#pragma unroll
        for (int j = 0; j < 4; ++j) acc[i][j] = 0.0f;

    // stage tile 0 into buf 0
    {
        float4 xv = *(const float4*)(x + (size_t)(m0 + sm) * D_MODEL + kb + sk4);
        float4 bv = *(const float4*)(BwT + (size_t)kb * N_STATE + tid * 4);
        xs[g][0][sk4 + 0][sm] = xv.x;
        xs[g][0][sk4 + 1][sm] = xv.y;
        xs[g][0][sk4 + 2][sm] = xv.z;
        xs[g][0][sk4 + 3][sm] = xv.w;
        *(float4*)(&bs[g][0][0][0] + tid * 4) = bv;
    }
    __syncthreads();

    for (int kt = 0; kt < 32; ++kt) {
        const int p = kt & 1;
        const bool more = (kt + 1 < 32);
        float4 xv, bv;
        if (more) {
            const int k0 = kb + (kt + 1) * 16;
            xv = *(const float4*)(x + (size_t)(m0 + sm) * D_MODEL + k0 + sk4);
            bv = *(const float4*)(BwT + (size_t)k0 * N_STATE + tid * 4);
        }

#pragma unroll
        for (int kk = 0; kk < 16; ++kk) {
            const float4 ap = *(const float4*)(&xs[g][p][kk][r * 4]);
            const float4 bq = *(const float4*)(&bs[g][p][kk][c * 4]);
            acc[0][0] = fmaf(ap.x, bq.x, acc[0][0]);
            acc[0][1] = fmaf(ap.x, bq.y, acc[0][1]);
            acc[0][2] = fmaf(ap.x, bq.z, acc[0][2]);
            acc[0][3] = fmaf(ap.x, bq.w, acc[0][3]);
            acc[1][0] = fmaf(ap.y, bq.x, acc[1][0]);
            acc[1][1] = fmaf(ap.y, bq.y, acc[1][1]);
            acc[1][2] = fmaf(ap.y, bq.z, acc[1][2]);
            acc[1][3] = fmaf(ap.y, bq.w, acc[1][3]);
            acc[2][0] = fmaf(ap.z, bq.x, acc[2][0]);
            acc[2][1] = fmaf(ap.z, bq.y, acc[2][1]);
            acc[2][2] = fmaf(ap.z, bq.z, acc[2][2]);
            acc[2][3] = fmaf(ap.z, bq.w, acc[2][3]);
            acc[3][0] = fmaf(ap.w, bq.x, acc[3][0]);
            acc[3][1] = fmaf(ap.w, bq.y, acc[3][1]);
            acc[3][2] = fmaf(ap.w, bq.z, acc[3][2]);
            acc[3][3] = fmaf(ap.w, bq.w, acc[3][3]);
        }

        if (more) {
            const int q = 1 - p;
            xs[g][q][sk4 + 0][sm] = xv.x;
            xs[g][q][sk4 + 1][sm] = xv.y;
            xs[g][q][sk4 + 2][sm] = xv.z;
            xs[g][q][sk4 + 3][sm] = xv.w;
            *(float4*)(&bs[g][q][0][0] + tid * 4) = bv;
        }
        __syncthreads();
    }

    // combine halves: group 1 publishes partials, group 0 reduces + stores
    if (g == 1) {
#pragma unroll
        for (int i = 0; i < 4; ++i)
#pragma unroll
            for (int j = 0; j < 4; ++j)
                accb[i * 4 + j][tid] = acc[i][j];
    }
    __syncthreads();
    if (g == 0) {
#pragma unroll
        for (int i = 0; i < 4; ++i) {
            float o0 = acc[i][0] + accb[i * 4 + 0][tid];
            float o1 = acc[i][1] + accb[i * 4 + 1][tid];
            float o2 = acc[i][2] + accb[i * 4 + 2][tid];
            float o3 = acc[i][3] + accb[i * 4 + 3][tid];
            *(float4*)(&bt[(size_t)(m0 + r * 4 + i) * N_STATE + c * 4]) =
                make_float4(o0, o1, o2, o3);
            float bm = fminf(fminf(o0, o1), fminf(o2, o3));
            bm = dpp_min<0xB1>(bm);  bm = dpp_min<0x4E>(bm);
            bm = dpp_min<0x141>(bm); bm = dpp_min<0x140>(bm);
            if (c == 0) btmin[m0 + r * 4 + i] = bm;
        }
    }
}

// ---------------------------------------------------------------------------
// k2: sequential scan, time-segmented 2x. grid 2048 = 16 batch x 64 dgroup x
// 2 segments -> 8 blocks/CU, 32 waves/CU.
// Saturation fast path (round-3, verified): pred(s,d) = x*max(btmin,0) >=
// SAT_T => h clamps to exactly 1.0f, y bitwise csum[d]; k2 stores only
// pred-false rows (~0.4%), k3 reconstructs the rest.
// Round 8: (a) DEPTH-2 PREFETCH — loads for chunk ch+2 issued at the top of
// iteration ch, held in regs, written to LDS after the inner loop; the
// issue->waitcnt gap becomes ~2 inner loops, covering HBM latency (round-7
// depth-1 stalled every chunk at the staging write). (b) BLOCK CHUNK SKIP —
// the loop barrier is __syncthreads_and(my staged px >= SAT_T): when ALL 256
// (step,chain) preds of the next chunk are saturated (~36% of chunks), the
// inner loop collapses to h=1 (exactly what the per-group votes would have
// produced -> bitwise identical output).
// ---------------------------------------------------------------------------
__global__ __launch_bounds__(256, 8) void k2_scan(
        const float* __restrict__ x, const float* __restrict__ bt,
        const float* __restrict__ btmin,
        const float* __restrict__ A_sig, const float* __restrict__ Cs,
        float* __restrict__ y_raw) {
    const int t    = threadIdx.x;
    const int lane = t & 63;
    const int wv   = t >> 6;
    const int nq   = lane & 15;            // n-quad -> n = nq*4
    const int cl   = wv * 4 + (lane >> 4); // chain within block, 0..15
    const int bid  = blockIdx.x;
    const int seg  = bid & 1;
    const int dg   = (bid >> 1) & 63;
    const int b    = bid >> 7;
    const int d0   = dg * 16;
    const int d    = d0 + cl;

    const int nWarm  = seg ? (WARM / CS) : 0;     // 4 or 0
    const int nTot   = nWarm + (SEGLEN / CS);     // 36 or 32
    const int sStart = seg * SEGLEN - nWarm * CS; // 0 or 448

    __shared__ __align__(16) float lbt [2][CS * 64];    // 2 x 4 KB bt tile
    __shared__ __align__(16) float lx  [2][CS * 16];    // 2 x 1 KB x[step][chain]
    __shared__ __align__(16) float lpxT[2][16 * LPS];   // 2 x 1.25 KB px[chain][step(+pad)]

    const float4 av = *(const float4*)(A_sig + (size_t)d * N_STATE + nq * 4);
    const float4 cv = *(const float4*)(Cs    + (size_t)d * N_STATE + nq * 4);

    float h0 = 0.f, h1 = 0.f, h2 = 0.f, h3 = 0.f;

    const float* btp  = bt    + (size_t)b * SEQ * N_STATE + (size_t)sStart * N_STATE;
    const float* btmp = btmin + (size_t)b * SEQ + sStart;
    const float* xpp  = x + (size_t)b * SEQ * D_MODEL + (size_t)sStart * D_MODEL + d0;
    float* ystore = y_raw + (size_t)b * SEQ * D_MODEL + (size_t)seg * SEGLEN * D_MODEL + d;

    const int xst = t >> 4;          // staging: step 0..15
    const int xdd = t & 15;          // staging: chain

    // stage chunk 0 into buf 0 (write immediately; keep px for the vote)
    float px0;
    {
        float4 b4 = *(const float4*)(btp + t * 4);
        float  xv = xpp[(size_t)xst * D_MODEL + xdd];
        float  bm = fmaxf(btmp[xst], 0.f);   // clamp: pred => bm>0 and x>0
        *(float4*)(&lbt[0][t * 4]) = b4;
        lx[0][t] = xv;
        px0 = xv * bm;
        lpxT[0][xdd * LPS + xst] = px0;
    }
    btp  += CS * N_STATE;
    btmp += CS;
    xpp  += (size_t)CS * D_MODEL;

    // issue loads for chunk 1 into regs (depth-2 pipeline prologue)
    float4 nb1; float nx1 = 0.f, npx1 = 0.f;
    if (1 < nTot) {
        nb1  = *(const float4*)(btp + t * 4);
        nx1  = xpp[(size_t)xst * D_MODEL + xdd];
        npx1 = nx1 * fmaxf(btmp[xst], 0.f);
        btp  += CS * N_STATE;
        btmp += CS;
        xpp  += (size_t)CS * D_MODEL;
    }

    // staging barrier doubles as the chunk-0 all-fast vote
    int fastCur = __syncthreads_and(px0 >= SAT_T);

    for (int ch = 0; ch < nTot; ++ch) {
        const int p = ch & 1;
        const bool more1 = (ch + 1 < nTot);
        const bool more2 = (ch + 2 < nTot);

        // issue loads for chunk ch+2
        float4 nb2; float nx2 = 0.f, npx2 = 0.f;
        if (more2) {
            nb2  = *(const float4*)(btp + t * 4);
            nx2  = xpp[(size_t)xst * D_MODEL + xdd];
            npx2 = nx2 * fmaxf(btmp[xst], 0.f);
            btp  += CS * N_STATE;
            btmp += CS;
            xpp  += (size_t)CS * D_MODEL;
        }

        // inner loop on buf p (chunk ch)
        if (fastCur) {
            h0 = h1 = h2 = h3 = 1.f;                 // exact: all preds true
            if (ch >= nWarm) ystore += (size_t)CS * D_MODEL;   // nothing stored
        } else {
            const float* Lb = lbt[p];
            const float* Lx = lx [p];
            const float* Lp = &lpxT[p][cl * LPS];   // this lane's chain

            if (ch < nWarm) {
#pragma unroll
                for (int g = 0; g < 4; ++g) {
                    const float4 pq = *(const float4*)(Lp + g * 4);
                    const float qmin = fminf(fminf(pq.x, pq.y), fminf(pq.z, pq.w));
                    if (__all(qmin >= SAT_T)) { h0 = h1 = h2 = h3 = 1.f; continue; }
                    const float pmv[4] = {pq.x, pq.y, pq.z, pq.w};
#pragma unroll
                    for (int j = 0; j < 4; ++j) {
                        const int i = g * 4 + j;
                        const float pm = pmv[j];
                        if (__all(pm >= SAT_T)) { h0 = h1 = h2 = h3 = 1.f; continue; }
                        const float  xt = Lx[i * 16 + cl];
                        const float4 bv = *(const float4*)(Lb + i * 64 + nq * 4);
                        h0 = CLAMP01(fmaf(h0, av.x, bv.x * xt));
                        h1 = CLAMP01(fmaf(h1, av.y, bv.y * xt));
                        h2 = CLAMP01(fmaf(h2, av.z, bv.z * xt));
                        h3 = CLAMP01(fmaf(h3, av.w, bv.w * xt));
                    }
                }
            } else {
#pragma unroll
                for (int g = 0; g < 4; ++g) {
                    const float4 pq = *(const float4*)(Lp + g * 4);
                    const float qmin = fminf(fminf(pq.x, pq.y), fminf(pq.z, pq.w));
                    if (__all(qmin >= SAT_T)) { h0 = h1 = h2 = h3 = 1.f; continue; }
                    const float pmv[4] = {pq.x, pq.y, pq.z, pq.w};
#pragma unroll
                    for (int j = 0; j < 4; ++j) {
                        const int i = g * 4 + j;
                        const float pm = pmv[j];
                        if (__all(pm >= SAT_T)) { h0 = h1 = h2 = h3 = 1.f; continue; }
                        const float  xt = Lx[i * 16 + cl];
                        const float4 bv = *(const float4*)(Lb + i * 64 + nq * 4);
                        h0 = CLAMP01(fmaf(h0, av.x, bv.x * xt));
                        h1 = CLAMP01(fmaf(h1, av.y, bv.y * xt));
                        h2 = CLAMP01(fmaf(h2, av.z, bv.z * xt));
                        h3 = CLAMP01(fmaf(h3, av.w, bv.w * xt));
                        float y = fmaf(h0, cv.x, h1 * cv.y) + fmaf(h2, cv.z, h3 * cv.w);
                        y = dpp_add<0xB1>(y);
                        y = dpp_add<0x4E>(y);
                        y = dpp_add<0x141>(y);
                        y = dpp_add<0x140>(y);
                        // store only pred-false rows (row-uniform condition);
                        // pred-true rows are reconstructed as csum[d] in k3.
                        if (nq == 0 && !(pm >= SAT_T)) ystore[(size_t)i * D_MODEL] = y;
                    }
                }
                ystore += (size_t)CS * D_MODEL;
            }
        }

        // write chunk ch+1 into buf q (loads issued ~2 iterations ago)
        if (more1) {
            const int q = 1 - p;
            *(float4*)(&lbt[q][t * 4]) = nb1;
            lx[q][t] = nx1;
            lpxT[q][xdd * LPS + xst] = npx1;
        }

        // barrier + all-fast vote for chunk ch+1; rotate prefetch regs
        fastCur = __syncthreads_and(more1 ? (npx1 >= SAT_T) : 1);
        nb1 = nb2; nx1 = nx2; npx1 = npx2;
    }
}

// ---------------------------------------------------------------------------
// k3: per (b,s) row of 1024: reconstruct y (pred ? csum[d] : stored y_raw),
// two-pass layernorm over d, scale by gs, add residual x, clip. In-place.
// Single conditional float4 load (taken by ~1.6% of lanes).
// ---------------------------------------------------------------------------
__global__ __launch_bounds__(256, 1) void k3_norm(
        const float* __restrict__ x, const float* __restrict__ gs,
        const float* __restrict__ btmin, const float* __restrict__ csum,
        float* __restrict__ y) {
    const int row = blockIdx.x;           // b*SEQ + s
    const int t   = threadIdx.x;
    const size_t base = (size_t)row * D_MODEL + t * 4;
    const float bm = fmaxf(btmin[row], 0.f);   // same clamp+product as k2

    float4 xv  = *(const float4*)(x + base);
    float4 cs4 = *(const float4*)(csum + t * 4);
    const bool p0 = (xv.x * bm >= SAT_T);
    const bool p1 = (xv.y * bm >= SAT_T);
    const bool p2 = (xv.z * bm >= SAT_T);
    const bool p3 = (xv.w * bm >= SAT_T);
    float y0 = cs4.x, y1 = cs4.y, y2 = cs4.z, y3 = cs4.w;
    if (!(p0 && p1 && p2 && p3)) {
        float4 ld = *(const float4*)(y + base);
        if (!p0) y0 = ld.x;
        if (!p1) y1 = ld.y;
        if (!p2) y2 = ld.z;
        if (!p3) y3 = ld.w;
    }

    float s1 = (y0 + y1) + (y2 + y3);
#pragma unroll
    for (int off = 32; off > 0; off >>= 1) s1 += __shfl_xor(s1, off);

    __shared__ float red[8];
    const int w = t >> 6;
    if ((t & 63) == 0) red[w] = s1;
    __syncthreads();
    const float mu = (red[0] + red[1] + red[2] + red[3]) * (1.0f / (float)D_MODEL);

    const float dx0 = y0 - mu, dx1 = y1 - mu, dx2 = y2 - mu, dx3 = y3 - mu;
    float s2 = (dx0 * dx0 + dx1 * dx1) + (dx2 * dx2 + dx3 * dx3);
#pragma unroll
    for (int off = 32; off > 0; off >>= 1) s2 += __shfl_xor(s2, off);
    if ((t & 63) == 0) red[4 + w] = s2;
    __syncthreads();
    const float var = (red[4] + red[5] + red[6] + red[7]) * (1.0f / (float)D_MODEL);
    const float rs  = 1.0f / sqrtf(var + 1e-5f);

    float4 gv = *(const float4*)(gs + t * 4);
    float4 o;
    o.x = fminf(fmaxf(dx0 * rs * gv.x + xv.x, 0.f), 1.f);
    o.y = fminf(fmaxf(dx1 * rs * gv.y + xv.y, 0.f), 1.f);
    o.z = fminf(fmaxf(dx2 * rs * gv.z + xv.z, 0.f), 1.f);
    o.w = fminf(fmaxf(dx3 * rs * gv.w + xv.w, 0.f), 1.f);
    *(float4*)(y + base) = o;
}

// ---------------------------------------------------------------------------
extern "C" void kernel_launch(void* const* d_in, const int* in_sizes, int n_in,
                              void* d_out, int out_size, void* d_ws, size_t ws_size,
                              hipStream_t stream) {
    (void)in_sizes; (void)n_in; (void)out_size; (void)ws_size;
    const float* x     = (const float*)d_in[0];
    const float* A     = (const float*)d_in[1];
    const float* W_B   = (const float*)d_in[2];
    const float* W_C   = (const float*)d_in[3];
    const float* gamma = (const float*)d_in[4];
    float* out = (float*)d_out;
    float* ws  = (float*)d_ws;

    float* bt    = ws;                                       // 1048576 floats
    float* A_sig = ws + 1048576;                             // 65536
    float* BwT   = ws + 1048576 + 65536;                     // 65536
    float* Cs    = ws + 1048576 + 2 * 65536;                 // 65536
    float* gs    = ws + 1048576 + 3 * 65536;                 // 1024
    float* btmin = ws + 1048576 + 3 * 65536 + 1024;          // 16384
    float* csum  = ws + 1048576 + 3 * 65536 + 1024 + 16384;  // 1024

    k0_precompute<<<dim3(260), dim3(256), 0, stream>>>(A, W_B, W_C, gamma,
                                                       A_sig, BwT, Cs, gs, csum);
    k1_bt_gemm<<<dim3(256), dim3(512), 0, stream>>>(x, BwT, bt, btmin);
    k2_scan<<<dim3(2048), dim3(256), 0, stream>>>(x, bt, btmin, A_sig, Cs, out);
    k3_norm<<<dim3(BATCH * SEQ), dim3(256), 0, stream>>>(x, gs, btmin, csum, out);
}

// Round 10
// 202.409 us; speedup vs baseline: 1.0652x; 1.0652x over previous
//
#include <hip/hip_runtime.h>
#include <math.h>

#define D_MODEL 1024
#define N_STATE 64
#define BATCH   16
#define SEQ     1024
#define CS      16          // scan steps per LDS chunk
#define SEGLEN  512         // steps stored per segment
#define WARM    64          // warmup steps for segment 1 (0.7311^64 ~ 2e-9)
#define SAT_T   1.0001f     // saturation margin (covers fp32 rounding)
#define LPS     20          // lpxT row stride (pad; rows stay 16B-aligned)

__device__ __forceinline__ float sigmoidf_dev(float v) {
    return 1.0f / (1.0f + expf(-v));
}

// DPP add: v += v[partner] within an aligned 16-lane row. Pure VALU, no LDS.
// 0xB1 = quad_perm [1,0,3,2] (xor1), 0x4E = quad_perm [2,3,0,1] (xor2),
// 0x141 = row_half_mirror (acts as xor4 on quad-uniform values),
// 0x140 = row_mirror (acts as xor8 on half-row-uniform values).
template<int CTRL>
__device__ __forceinline__ float dpp_add(float v) {
    int s = __builtin_amdgcn_update_dpp(0, __float_as_int(v), CTRL, 0xF, 0xF, true);
    return v + __int_as_float(s);
}

template<int CTRL>
__device__ __forceinline__ float dpp_min(float v) {
    int s = __builtin_amdgcn_update_dpp(0, __float_as_int(v), CTRL, 0xF, 0xF, true);
    return fminf(v, __int_as_float(s));
}

#define CLAMP01(v) __builtin_amdgcn_fmed3f((v), 0.0f, 1.0f)

// ---------------------------------------------------------------------------
// k0 (merged): blocks 0..255 precompute sigmoid(A), BwT, Cs, gs.
// Blocks 256..259 compute csum[d] = sum_n sigmoid(W_C[d][n]) in EXACTLY the
// op order of k2's slow path with h==1 (per-quad (c0+c1)+(c2+c3), balanced
// XOR tree off=1,2,4,8) — sigmoidf_dev(W_C[i]) is bitwise-identical to the
// Cs value k2 uses, so the substitution in k3 stays bit-exact.
// ---------------------------------------------------------------------------
__global__ __launch_bounds__(256) void k0_precompute(
        const float* __restrict__ A, const float* __restrict__ W_B,
        const float* __restrict__ W_C, const float* __restrict__ gamma,
        float* __restrict__ A_sig, float* __restrict__ BwT,
        float* __restrict__ Cs, float* __restrict__ gs,
        float* __restrict__ csum) {
    const int bid = blockIdx.x;
    const int t   = threadIdx.x;
    if (bid < 256) {
        int i = bid * 256 + t;
        A_sig[i] = sigmoidf_dev(A[i]);
        Cs[i]    = sigmoidf_dev(W_C[i]);
        int d = i >> 6, n = i & 63;                  // i = d*64 + n
        BwT[i] = sigmoidf_dev(W_B[n * D_MODEL + d]); // W_B is [N, D]
        if (i < D_MODEL) gs[i] = sigmoidf_dev(gamma[i]);
    } else {
        int d = (bid - 256) * 256 + t;               // 0..1023
        const float4* c = (const float4*)(W_C + (size_t)d * N_STATE);
        float w[16];
#pragma unroll
        for (int q = 0; q < 16; ++q) {
            float4 v = c[q];
            w[q] = (sigmoidf_dev(v.x) + sigmoidf_dev(v.y)) +
                   (sigmoidf_dev(v.z) + sigmoidf_dev(v.w));
        }
#pragma unroll
        for (int off = 1; off < 16; off <<= 1) {
            float tmp[16];
#pragma unroll
            for (int q = 0; q < 16; ++q) tmp[q] = w[q] + w[q ^ off];
#pragma unroll
            for (int q = 0; q < 16; ++q) w[q] = tmp[q];
        }
        csum[d] = w[0];
    }
}

// ---------------------------------------------------------------------------
// k1: bt[m][n] = sum_d x[m][d] * BwT[d][n]  (M=16384, K=1024, N=64, fp32)
// Split-K within the block (round 7). Block = 512 threads (8 waves); group
// g = t>>8 accumulates k in [g*512, g*512+512) sequentially (kt asc, kk asc).
// Group 1 publishes partials via LDS scalar planes; group 0 adds, stores bt
// and btmin. Grid 256 -> 8 waves/CU, 2 waves/SIMD, 2 B/FMA.
// ---------------------------------------------------------------------------
__global__ __launch_bounds__(512) void k1_bt_gemm(
        const float* __restrict__ x, const float* __restrict__ BwT,
        float* __restrict__ bt, float* __restrict__ btmin) {
    __shared__ float xs[2][2][16][68];   // [grp][buf][k][m(64)+4 pad]
    __shared__ float bs[2][2][16][64];   // [grp][buf][k][n]
    __shared__ float accb[16][256];      // group-1 partials, scalar planes

    const int t   = threadIdx.x;
    const int g   = t >> 8;           // k-half group
    const int tid = t & 255;
    const int r   = tid >> 4;         // 0..15 -> m rows r*4 .. r*4+3
    const int c   = tid & 15;         // 0..15 -> n quad c*4
    const int m0  = blockIdx.x * 64;
    const int kb  = g * 512;          // k base for this group

    const int sm  = tid >> 2;         // staging: m row 0..63
    const int sk4 = (tid & 3) * 4;    // staging: k quad 0,4,8,12

    float acc[4][4];
#pragma unroll
    for (int i = 0; i < 4; ++i)
#pragma unroll
        for (int j = 0; j < 4; ++j) acc[i][j] = 0.0f;

    // stage tile 0 into buf 0
    {
        float4 xv = *(const float4*)(x + (size_t)(m0 + sm) * D_MODEL + kb + sk4);
        float4 bv = *(const float4*)(BwT + (size_t)kb * N_STATE + tid * 4);
        xs[g][0][sk4 + 0][sm] = xv.x;
        xs[g][0][sk4 + 1][sm] = xv.y;
        xs[g][0][sk4 + 2][sm] = xv.z;
        xs[g][0][sk4 + 3][sm] = xv.w;
        *(float4*)(&bs[g][0][0][0] + tid * 4) = bv;
    }
    __syncthreads();

    for (int kt = 0; kt < 32; ++kt) {
        const int p = kt & 1;
        const bool more = (kt + 1 < 32);
        float4 xv, bv;
        if (more) {
            const int k0 = kb + (kt + 1) * 16;
            xv = *(const float4*)(x + (size_t)(m0 + sm) * D_MODEL + k0 + sk4);
            bv = *(const float4*)(BwT + (size_t)k0 * N_STATE + tid * 4);
        }

#pragma unroll
        for (int kk = 0; kk < 16; ++kk) {
            const float4 ap = *(const float4*)(&xs[g][p][kk][r * 4]);
            const float4 bq = *(const float4*)(&bs[g][p][kk][c * 4]);
            acc[0][0] = fmaf(ap.x, bq.x, acc[0][0]);
            acc[0][1] = fmaf(ap.x, bq.y, acc[0][1]);
            acc[0][2] = fmaf(ap.x, bq.z, acc[0][2]);
            acc[0][3] = fmaf(ap.x, bq.w, acc[0][3]);
            acc[1][0] = fmaf(ap.y, bq.x, acc[1][0]);
            acc[1][1] = fmaf(ap.y, bq.y, acc[1][1]);
            acc[1][2] = fmaf(ap.y, bq.z, acc[1][2]);
            acc[1][3] = fmaf(ap.y, bq.w, acc[1][3]);
            acc[2][0] = fmaf(ap.z, bq.x, acc[2][0]);
            acc[2][1] = fmaf(ap.z, bq.y, acc[2][1]);
            acc[2][2] = fmaf(ap.z, bq.z, acc[2][2]);
            acc[2][3] = fmaf(ap.z, bq.w, acc[2][3]);
            acc[3][0] = fmaf(ap.w, bq.x, acc[3][0]);
            acc[3][1] = fmaf(ap.w, bq.y, acc[3][1]);
            acc[3][2] = fmaf(ap.w, bq.z, acc[3][2]);
            acc[3][3] = fmaf(ap.w, bq.w, acc[3][3]);
        }

        if (more) {
            const int q = 1 - p;
            xs[g][q][sk4 + 0][sm] = xv.x;
            xs[g][q][sk4 + 1][sm] = xv.y;
            xs[g][q][sk4 + 2][sm] = xv.z;
            xs[g][q][sk4 + 3][sm] = xv.w;
            *(float4*)(&bs[g][q][0][0] + tid * 4) = bv;
        }
        __syncthreads();
    }

    // combine halves: group 1 publishes partials, group 0 reduces + stores
    if (g == 1) {
#pragma unroll
        for (int i = 0; i < 4; ++i)
#pragma unroll
            for (int j = 0; j < 4; ++j)
                accb[i * 4 + j][tid] = acc[i][j];
    }
    __syncthreads();
    if (g == 0) {
#pragma unroll
        for (int i = 0; i < 4; ++i) {
            float o0 = acc[i][0] + accb[i * 4 + 0][tid];
            float o1 = acc[i][1] + accb[i * 4 + 1][tid];
            float o2 = acc[i][2] + accb[i * 4 + 2][tid];
            float o3 = acc[i][3] + accb[i * 4 + 3][tid];
            *(float4*)(&bt[(size_t)(m0 + r * 4 + i) * N_STATE + c * 4]) =
                make_float4(o0, o1, o2, o3);
            float bm = fminf(fminf(o0, o1), fminf(o2, o3));
            bm = dpp_min<0xB1>(bm);  bm = dpp_min<0x4E>(bm);
            bm = dpp_min<0x141>(bm); bm = dpp_min<0x140>(bm);
            if (c == 0) btmin[m0 + r * 4 + i] = bm;
        }
    }
}

// ---------------------------------------------------------------------------
// k2: sequential scan, time-segmented 2x. grid 2048 = 16 batch x 64 dgroup x
// 2 segments -> 8 blocks/CU, 32 waves/CU.  [round-7 version, verbatim revert:
// round-8's __syncthreads_and chunk-vote cost ~2 barriers + LDS reduce per
// chunk (~28K cyc/CU), regressing 46.3 -> 57.9 us.]
// Saturation fast path (round-3, verified): pred(s,d) = x*max(btmin,0) >=
// SAT_T => h clamps to exactly 1.0f, y bitwise csum[d]; k2 stores only
// pred-false rows (~0.4%), k3 reconstructs the rest.
// Round 4: px transposed [chain][LPS]; 4-step groups take ONE float4 read +
// 3 min + 1 vote when the wave's quad is all-fast (~94%), falling back to
// the identical per-step path for mixed quads.
// ---------------------------------------------------------------------------
__global__ __launch_bounds__(256, 8) void k2_scan(
        const float* __restrict__ x, const float* __restrict__ bt,
        const float* __restrict__ btmin,
        const float* __restrict__ A_sig, const float* __restrict__ Cs,
        float* __restrict__ y_raw) {
    const int t    = threadIdx.x;
    const int lane = t & 63;
    const int wv   = t >> 6;
    const int nq   = lane & 15;            // n-quad -> n = nq*4
    const int cl   = wv * 4 + (lane >> 4); // chain within block, 0..15
    const int bid  = blockIdx.x;
    const int seg  = bid & 1;
    const int dg   = (bid >> 1) & 63;
    const int b    = bid >> 7;
    const int d0   = dg * 16;
    const int d    = d0 + cl;

    const int nWarm  = seg ? (WARM / CS) : 0;     // 4 or 0
    const int nTot   = nWarm + (SEGLEN / CS);     // 36 or 32
    const int sStart = seg * SEGLEN - nWarm * CS; // 0 or 448

    __shared__ __align__(16) float lbt [2][CS * 64];    // 2 x 4 KB bt tile
    __shared__ __align__(16) float lx  [2][CS * 16];    // 2 x 1 KB x[step][chain]
    __shared__ __align__(16) float lpxT[2][16 * LPS];   // 2 x 1.25 KB px[chain][step(+pad)]

    const float4 av = *(const float4*)(A_sig + (size_t)d * N_STATE + nq * 4);
    const float4 cv = *(const float4*)(Cs    + (size_t)d * N_STATE + nq * 4);

    float h0 = 0.f, h1 = 0.f, h2 = 0.f, h3 = 0.f;

    const float* btp  = bt    + (size_t)b * SEQ * N_STATE + (size_t)sStart * N_STATE;
    const float* btmp = btmin + (size_t)b * SEQ + sStart;
    const float* xpp  = x + (size_t)b * SEQ * D_MODEL + (size_t)sStart * D_MODEL + d0;
    float* ystore = y_raw + (size_t)b * SEQ * D_MODEL + (size_t)seg * SEGLEN * D_MODEL + d;

    const int xst = t >> 4;          // staging: step 0..15
    const int xdd = t & 15;          // staging: chain

    // stage chunk 0 into buf 0
    {
        float4 b4 = *(const float4*)(btp + t * 4);
        float  xv = xpp[(size_t)xst * D_MODEL + xdd];
        float  bm = fmaxf(btmp[xst], 0.f);   // clamp: pred => bm>0 and x>0
        *(float4*)(&lbt[0][t * 4]) = b4;
        lx[0][t] = xv;
        lpxT[0][xdd * LPS + xst] = xv * bm;
    }
    btp  += CS * N_STATE;
    btmp += CS;
    xpp  += (size_t)CS * D_MODEL;
    __syncthreads();

    for (int ch = 0; ch < nTot; ++ch) {
        const int p = ch & 1;
        float4 nb; float nx, npx;
        const bool more = (ch + 1 < nTot);
        if (more) {
            nb  = *(const float4*)(btp + t * 4);
            nx  = xpp[(size_t)xst * D_MODEL + xdd];
            npx = nx * fmaxf(btmp[xst], 0.f);
            btp  += CS * N_STATE;
            btmp += CS;
            xpp  += (size_t)CS * D_MODEL;
        }

        const float* Lb = lbt[p];
        const float* Lx = lx [p];
        const float* Lp = &lpxT[p][cl * LPS];   // this lane's chain, 16 steps

        if (ch < nWarm) {
#pragma unroll
            for (int g = 0; g < 4; ++g) {
                const float4 pq = *(const float4*)(Lp + g * 4);
                const float qmin = fminf(fminf(pq.x, pq.y), fminf(pq.z, pq.w));
                if (__all(qmin >= SAT_T)) { h0 = h1 = h2 = h3 = 1.f; continue; }
                const float pmv[4] = {pq.x, pq.y, pq.z, pq.w};
#pragma unroll
                for (int j = 0; j < 4; ++j) {
                    const int i = g * 4 + j;
                    const float pm = pmv[j];
                    if (__all(pm >= SAT_T)) { h0 = h1 = h2 = h3 = 1.f; continue; }
                    const float  xt = Lx[i * 16 + cl];
                    const float4 bv = *(const float4*)(Lb + i * 64 + nq * 4);
                    h0 = CLAMP01(fmaf(h0, av.x, bv.x * xt));
                    h1 = CLAMP01(fmaf(h1, av.y, bv.y * xt));
                    h2 = CLAMP01(fmaf(h2, av.z, bv.z * xt));
                    h3 = CLAMP01(fmaf(h3, av.w, bv.w * xt));
                }
            }
        } else {
#pragma unroll
            for (int g = 0; g < 4; ++g) {
                const float4 pq = *(const float4*)(Lp + g * 4);
                const float qmin = fminf(fminf(pq.x, pq.y), fminf(pq.z, pq.w));
                if (__all(qmin >= SAT_T)) { h0 = h1 = h2 = h3 = 1.f; continue; }
                const float pmv[4] = {pq.x, pq.y, pq.z, pq.w};
#pragma unroll
                for (int j = 0; j < 4; ++j) {
                    const int i = g * 4 + j;
                    const float pm = pmv[j];
                    if (__all(pm >= SAT_T)) { h0 = h1 = h2 = h3 = 1.f; continue; }
                    const float  xt = Lx[i * 16 + cl];
                    const float4 bv = *(const float4*)(Lb + i * 64 + nq * 4);
                    h0 = CLAMP01(fmaf(h0, av.x, bv.x * xt));
                    h1 = CLAMP01(fmaf(h1, av.y, bv.y * xt));
                    h2 = CLAMP01(fmaf(h2, av.z, bv.z * xt));
                    h3 = CLAMP01(fmaf(h3, av.w, bv.w * xt));
                    float y = fmaf(h0, cv.x, h1 * cv.y) + fmaf(h2, cv.z, h3 * cv.w);
                    y = dpp_add<0xB1>(y);
                    y = dpp_add<0x4E>(y);
                    y = dpp_add<0x141>(y);
                    y = dpp_add<0x140>(y);
                    // store only pred-false rows (row-uniform condition);
                    // pred-true rows are reconstructed as csum[d] in k3.
                    if (nq == 0 && !(pm >= SAT_T)) ystore[(size_t)i * D_MODEL] = y;
                }
            }
            ystore += (size_t)CS * D_MODEL;
        }

        if (more) {
            const int q = 1 - p;
            *(float4*)(&lbt[q][t * 4]) = nb;
            lx[q][t] = nx;
            lpxT[q][xdd * LPS + xst] = npx;
        }
        __syncthreads();
    }
}

// ---------------------------------------------------------------------------
// k3: reconstruct y (pred ? csum[d] : stored y_raw), layernorm over d, scale
// by gs, add residual x, clip. Round 9: ONE WAVE PER ROW (4 rows/block,
// grid 4096) — lane holds 16 elements (4x float4, coalesced stride-256);
// mean/var via 6 __shfl_xor each; ZERO barriers, ZERO LDS (old version paid
// 2 x (LDS round-trip + __syncthreads) per 1024-element row).
// ---------------------------------------------------------------------------
__global__ __launch_bounds__(256) void k3_norm(
        const float* __restrict__ x, const float* __restrict__ gs,
        const float* __restrict__ btmin, const float* __restrict__ csum,
        float* __restrict__ y) {
    const int t    = threadIdx.x;
    const int wv   = t >> 6;
    const int lane = t & 63;
    const int row  = blockIdx.x * 4 + wv;     // b*SEQ + s
    const size_t rbase = (size_t)row * D_MODEL;
    const float bm = fmaxf(btmin[row], 0.f);  // same clamp+product as k2

    float4 xv[4], yv[4];
    float s1 = 0.f;
#pragma unroll
    for (int c = 0; c < 4; ++c) {
        const int doff = c * 256 + lane * 4;
        float4 xq = *(const float4*)(x + rbase + doff);
        float4 cq = *(const float4*)(csum + doff);
        const bool p0 = (xq.x * bm >= SAT_T);
        const bool p1 = (xq.y * bm >= SAT_T);
        const bool p2 = (xq.z * bm >= SAT_T);
        const bool p3 = (xq.w * bm >= SAT_T);
        float4 yq = cq;
        if (!(p0 && p1 && p2 && p3)) {
            float4 ld = *(const float4*)(y + rbase + doff);
            if (!p0) yq.x = ld.x;
            if (!p1) yq.y = ld.y;
            if (!p2) yq.z = ld.z;
            if (!p3) yq.w = ld.w;
        }
        xv[c] = xq;
        yv[c] = yq;
        s1 += (yq.x + yq.y) + (yq.z + yq.w);
    }
#pragma unroll
    for (int off = 32; off > 0; off >>= 1) s1 += __shfl_xor(s1, off);
    const float mu = s1 * (1.0f / (float)D_MODEL);

    float s2 = 0.f;
#pragma unroll
    for (int c = 0; c < 4; ++c) {
        const float d0 = yv[c].x - mu, d1 = yv[c].y - mu;
        const float d2 = yv[c].z - mu, d3 = yv[c].w - mu;
        s2 += (d0 * d0 + d1 * d1) + (d2 * d2 + d3 * d3);
    }
#pragma unroll
    for (int off = 32; off > 0; off >>= 1) s2 += __shfl_xor(s2, off);
    const float var = s2 * (1.0f / (float)D_MODEL);
    const float rs  = 1.0f / sqrtf(var + 1e-5f);

#pragma unroll
    for (int c = 0; c < 4; ++c) {
        const int doff = c * 256 + lane * 4;
        float4 gv = *(const float4*)(gs + doff);
        float4 o;
        o.x = fminf(fmaxf((yv[c].x - mu) * rs * gv.x + xv[c].x, 0.f), 1.f);
        o.y = fminf(fmaxf((yv[c].y - mu) * rs * gv.y + xv[c].y, 0.f), 1.f);
        o.z = fminf(fmaxf((yv[c].z - mu) * rs * gv.z + xv[c].z, 0.f), 1.f);
        o.w = fminf(fmaxf((yv[c].w - mu) * rs * gv.w + xv[c].w, 0.f), 1.f);
        *(float4*)(y + rbase + doff) = o;
    }
}

// ---------------------------------------------------------------------------
extern "C" void kernel_launch(void* const* d_in, const int* in_sizes, int n_in,
                              void* d_out, int out_size, void* d_ws, size_t ws_size,
                              hipStream_t stream) {
    (void)in_sizes; (void)n_in; (void)out_size; (void)ws_size;
    const float* x     = (const float*)d_in[0];
    const float* A     = (const float*)d_in[1];
    const float* W_B   = (const float*)d_in[2];
    const float* W_C   = (const float*)d_in[3];
    const float* gamma = (const float*)d_in[4];
    float* out = (float*)d_out;
    float* ws  = (float*)d_ws;

    float* bt    = ws;                                       // 1048576 floats
    float* A_sig = ws + 1048576;                             // 65536
    float* BwT   = ws + 1048576 + 65536;                     // 65536
    float* Cs    = ws + 1048576 + 2 * 65536;                 // 65536
    float* gs    = ws + 1048576 + 3 * 65536;                 // 1024
    float* btmin = ws + 1048576 + 3 * 65536 + 1024;          // 16384
    float* csum  = ws + 1048576 + 3 * 65536 + 1024 + 16384;  // 1024

    k0_precompute<<<dim3(260), dim3(256), 0, stream>>>(A, W_B, W_C, gamma,
                                                       A_sig, BwT, Cs, gs, csum);
    k1_bt_gemm<<<dim3(256), dim3(512), 0, stream>>>(x, BwT, bt, btmin);
    k2_scan<<<dim3(2048), dim3(256), 0, stream>>>(x, bt, btmin, A_sig, Cs, out);
    k3_norm<<<dim3(BATCH * SEQ / 4), dim3(256), 0, stream>>>(x, gs, btmin, csum, out);
}